// Round 14
// baseline (737.687 us; speedup 1.0000x reference)
//
#include <hip/hip_runtime.h>
#include <hip/hip_bf16.h>

typedef __attribute__((ext_vector_type(8))) short short8;   // 8 bf16 in 4 VGPRs
typedef __attribute__((ext_vector_type(4))) float f32x4;

#define N_HEAD 16
#define DMODEL 1024
#define LV 2048
#define LQ 2048
#define BATCH 2
#define HEAD_DIM 64

template <int N> struct IC { static constexpr int v = N; };

__device__ inline ushort f2bf(float f) {
    union { float f; unsigned u; } v; v.f = f;
    unsigned r = v.u + 0x7fffu + ((v.u >> 16) & 1u);   // RNE
    return (ushort)(r >> 16);
}
__device__ inline float bf2f(ushort h) {
    union { unsigned u; float f; } v; v.u = ((unsigned)h) << 16;
    return v.f;
}

// ---------------- cast f32 -> bf16 (same layout) ----------------
__global__ __launch_bounds__(256) void cast_bf16(const float* __restrict__ src,
                                                 ushort* __restrict__ dst, int n) {
    int i = (blockIdx.x * 256 + threadIdx.x) * 4;
    if (i < n) {
        float4 v = *(const float4*)(src + i);
        ushort4 o;
        o.x = f2bf(v.x); o.y = f2bf(v.y); o.z = f2bf(v.z); o.w = f2bf(v.w);
        *(ushort4*)(dst + i) = o;
    }
}

// ---------------- transpose + cast: src[z][R][C] f32 -> dst[z][C][R] bf16 ----
__global__ __launch_bounds__(256) void transpose_cast(const float* __restrict__ src,
                                                      ushort* __restrict__ dst,
                                                      int R, int C) {
    __shared__ float t[32][33];
    size_t zoff = (size_t)blockIdx.z * R * C;
    int c0 = blockIdx.x * 32, r0 = blockIdx.y * 32;
    int tx = threadIdx.x, ty = threadIdx.y;
#pragma unroll
    for (int i = 0; i < 4; ++i)
        t[ty + i * 8][tx] = src[zoff + (size_t)(r0 + ty + i * 8) * C + c0 + tx];
    __syncthreads();
#pragma unroll
    for (int i = 0; i < 4; ++i)
        dst[zoff + (size_t)(c0 + ty + i * 8) * R + r0 + tx] = f2bf(t[tx][ty + i * 8]);
}

// -------- 256x256 batched GEMM: r7 4-phase/K64 K-loop + r10 memory fixes -----
// (unchanged from round 13 -- 911 TF, MfmaUtil 41%, clean memory counters)
template <bool RELU, int LNA, int ZSH, bool BMFAST>
__global__ __launch_bounds__(512, 2) void gemm256(
    const ushort* __restrict__ A, const ushort* __restrict__ B,
    ushort* __restrict__ Cout, const float* __restrict__ bias,
    int K,
    long sA_b, long sA_h, long sB_b, long sB_h, long sC_z, int ldc, long sBias_h)
{
    __shared__ __align__(16) char smem[131072];

    // bijective XCD swizzle (gridDim.x % 8 == 0 always)
    const int gid = blockIdx.x;
    const int per = (int)gridDim.x >> 3;
    const int w = (gid & 7) * per + (gid >> 3);
    const int z = w >> ZSH;
    const int rem = w & ((1 << ZSH) - 1);
    int bm0, bn0;
    if (BMFAST) { bm0 = (rem & ((1 << LNA) - 1)) * 256; bn0 = (rem >> LNA) * 256; }
    else        { bn0 = (rem & ((1 << LNA) - 1)) * 256; bm0 = (rem >> LNA) * 256; }

    const int b = z & 1, h = z >> 1;
    A += (size_t)b * sA_b + (size_t)h * sA_h;
    B += (size_t)b * sB_b + (size_t)h * sB_h;
    const float* biasp = bias ? bias + (size_t)h * sBias_h : nullptr;

    const int T = threadIdx.x;
    const int lane = T & 63, wid = T >> 6;
    const int wr = wid >> 2, wc = wid & 3;          // wave -> (2 x 4) grid
    const int fr = lane & 15, fq = lane >> 4;
    const int laneoff = fr * 64 + ((fq * 16) ^ ((fr >> 3) << 5));   // swz read

    const char* pA0 = smem + 0     + wr * 8192 + laneoff;
    const char* pB0 = smem + 32768 + wc * 4096 + laneoff;
    const char* pA1 = pA0 + 65536;
    const char* pB1 = pB0 + 65536;

    const int s_row = T >> 2;                                   // 0..127
    const int s_csw = ((T & 3) * 16) ^ (((T >> 5) & 1) << 5);   // pre-swz col byte
    const ushort* gA = A + (size_t)(bm0 + s_row) * K + (s_csw >> 1);
    const ushort* gB = B + (size_t)(bn0 + s_row) * K + (s_csw >> 1);

    const int nt = K >> 6;      // K-steps of 64 (even, >= 4 here)

    auto stage = [&](int op, int kh, int db, int snext) {
        const ushort* g = op ? gB : gA;
        const size_t kbase = (size_t)snext * 64 + kh * 32;
        char* d = smem + db * 65536 + op * 32768 + kh * 16384 + (T << 4);
#pragma unroll
        for (int j = 0; j < 2; ++j) {
            __builtin_amdgcn_global_load_lds(
                (const __attribute__((address_space(1))) void*)(g + (size_t)j * 128 * K + kbase),
                (__attribute__((address_space(3))) void*)(d + j * 8192), 16, 0, 0);
        }
    };

    f32x4 acc[8][4];
#pragma unroll
    for (int m = 0; m < 8; ++m)
#pragma unroll
        for (int n = 0; n < 4; ++n)
#pragma unroll
            for (int j = 0; j < 4; ++j) acc[m][n][j] = 0.f;

    auto phase = [&](const char* pA, const char* pB, short8* bfr, int s, int db,
                     auto MH, auto KH, auto RDB, auto DOST, auto SOP, auto SKH, auto VM) {
        constexpr int mh = decltype(MH)::v, kh = decltype(KH)::v;
        short8 a[4];
#pragma unroll
        for (int i = 0; i < 4; ++i)
            a[i] = *(const short8*)(pA + kh * 16384 + (mh * 4 + i) * 1024);
        if constexpr (decltype(RDB)::v) {
#pragma unroll
            for (int n = 0; n < 4; ++n)
                bfr[n] = *(const short8*)(pB + kh * 16384 + n * 1024);
        }
        if constexpr (decltype(DOST)::v)
            stage(decltype(SOP)::v, decltype(SKH)::v, db ^ 1, s + 1);
        asm volatile("s_barrier" ::: "memory");
        asm volatile("s_waitcnt lgkmcnt(0)" ::: "memory");
        __builtin_amdgcn_sched_barrier(0);
        __builtin_amdgcn_s_setprio(1);
#pragma unroll
        for (int i = 0; i < 4; ++i)
#pragma unroll
            for (int n = 0; n < 4; ++n)
                acc[mh * 4 + i][n] = __builtin_amdgcn_mfma_f32_16x16x32_bf16(
                    a[i], bfr[n], acc[mh * 4 + i][n], 0, 0, 0);
        __builtin_amdgcn_s_setprio(0);
        __builtin_amdgcn_sched_barrier(0);
        constexpr int vm = decltype(VM)::v;
        if constexpr (vm == 4) asm volatile("s_waitcnt vmcnt(4)" ::: "memory");
        else if constexpr (vm == 0) asm volatile("s_waitcnt vmcnt(0)" ::: "memory");
        asm volatile("s_barrier" ::: "memory");
    };

    auto step_full = [&](int s, const char* pA, const char* pB, int db) {
        short8 bfr[4];
        phase(pA, pB, bfr, s, db, IC<0>{}, IC<0>{}, IC<1>{}, IC<1>{}, IC<0>{}, IC<0>{}, IC<-1>{});
        phase(pA, pB, bfr, s, db, IC<1>{}, IC<0>{}, IC<0>{}, IC<1>{}, IC<1>{}, IC<0>{}, IC<4>{});
        phase(pA, pB, bfr, s, db, IC<0>{}, IC<1>{}, IC<1>{}, IC<1>{}, IC<0>{}, IC<1>{}, IC<-1>{});
        phase(pA, pB, bfr, s, db, IC<1>{}, IC<1>{}, IC<0>{}, IC<1>{}, IC<1>{}, IC<1>{}, IC<4>{});
    };
    auto step_last = [&](int s, const char* pA, const char* pB, int db) {
        short8 bfr[4];
        phase(pA, pB, bfr, s, db, IC<0>{}, IC<0>{}, IC<1>{}, IC<0>{}, IC<0>{}, IC<0>{}, IC<-1>{});
        phase(pA, pB, bfr, s, db, IC<1>{}, IC<0>{}, IC<0>{}, IC<0>{}, IC<0>{}, IC<0>{}, IC<0>{});
        phase(pA, pB, bfr, s, db, IC<0>{}, IC<1>{}, IC<1>{}, IC<0>{}, IC<0>{}, IC<0>{}, IC<-1>{});
        phase(pA, pB, bfr, s, db, IC<1>{}, IC<1>{}, IC<0>{}, IC<0>{}, IC<0>{}, IC<0>{}, IC<-1>{});
    };

    stage(0, 0, 0, 0); stage(1, 0, 0, 0); stage(0, 1, 0, 0); stage(1, 1, 0, 0);
    asm volatile("s_waitcnt vmcnt(4)" ::: "memory");
    asm volatile("s_barrier" ::: "memory");

    for (int s = 0; s < nt - 2; s += 2) {
        step_full(s,     pA0, pB0, 0);
        step_full(s + 1, pA1, pB1, 1);
    }
    step_full(nt - 2, pA0, pB0, 0);   // stages step nt-1 into buf1
    step_last(nt - 1, pA1, pB1, 1);

    // ---- epilogue: two rounds by wr; full-line 16 B/lane stores (r10) ----
    asm volatile("s_waitcnt vmcnt(0) lgkmcnt(0)" ::: "memory");
    __builtin_amdgcn_s_barrier();
    ushort* C = Cout + (size_t)z * sC_z;
    const int col0 = bn0 + wc * 64;
    const int rl = lane >> 3, cb = lane & 7;
#pragma unroll
    for (int r = 0; r < 2; ++r) {
        if (wr == r) {
            char* eb = smem + wc * 18432;          // 128 rows x 144 B
#pragma unroll
            for (int n = 0; n < 4; ++n) {
                const float bvv = biasp ? biasp[col0 + n * 16 + fr] : 0.f;
#pragma unroll
                for (int m = 0; m < 8; ++m) {
#pragma unroll
                    for (int j = 0; j < 4; ++j) {
                        float val = acc[m][n][j] + bvv;
                        if (RELU) val = fmaxf(val, 0.f);
                        *(ushort*)(eb + (m * 16 + fq * 4 + j) * 144 + (n * 16 + fr) * 2) = f2bf(val);
                    }
                }
            }
            asm volatile("s_waitcnt lgkmcnt(0)" ::: "memory");   // per-wave region
            const int row0 = bm0 + r * 128;
#pragma unroll
            for (int i = 0; i < 16; ++i) {
                short8 vv = *(const short8*)(eb + (i * 8 + rl) * 144 + cb * 16);
                *(short8*)(C + (size_t)(row0 + i * 8 + rl) * ldc + col0 + cb * 8) = vv;
            }
        }
        __builtin_amdgcn_s_barrier();
    }
}

// -------- fused LayerNorm + projection:  out = LN(agg) @ WpT^T + bp ----------
// SINGLE-READ version (r14): each lane keeps its full 256-elem row-slice in
// registers (32 x short8 = 128 VGPR), computes stats from the register copy,
// then normalizes in-register and feeds the MFMA.  agg read ONCE from HBM/L3.
__global__ __launch_bounds__(256) void lnproj_kernel(const ushort* __restrict__ agg,
                                                     const ushort* __restrict__ WpT,
                                                     const float* __restrict__ gamma,
                                                     const float* __restrict__ beta,
                                                     const float* __restrict__ bp,
                                                     float* __restrict__ out,
                                                     int h_base) {
    const int z = blockIdx.y, b = z & 1, hg = h_base + (z >> 1);
    const int wid = threadIdx.x >> 6, lane = threadIdx.x & 63;
    const int fr = lane & 15, fq = lane >> 4;
    const int m0 = (blockIdx.x * 4 + wid) * 16;

    const ushort* Arow = agg + ((size_t)z * 2048 + m0 + fr) * 1024 + fq * 8;

    // single pass: load row-slice into registers, accumulate stats
    short8 a[32];
    float s = 0.f, s2 = 0.f;
#pragma unroll
    for (int kt = 0; kt < 32; ++kt) {
        a[kt] = *(const short8*)(Arow + kt * 32);
#pragma unroll
        for (int j = 0; j < 8; ++j) { float x = bf2f((ushort)a[kt][j]); s += x; s2 += x * x; }
    }
    s  += __shfl_xor(s, 16, 64);  s2 += __shfl_xor(s2, 16, 64);
    s  += __shfl_xor(s, 32, 64);  s2 += __shfl_xor(s2, 32, 64);
    const float mu  = s * (1.0f / 1024.0f);
    const float var = s2 * (1.0f / 1024.0f) - mu * mu;
    const float rs  = rsqrtf(fmaxf(var, 0.f) + 1e-5f);

    const ushort* Bbase = WpT + (size_t)hg * 64 * 1024 + (size_t)fr * 1024 + fq * 8;
    const float* gp = gamma + (size_t)hg * 1024 + fq * 8;
    const float* bt = beta  + (size_t)hg * 1024 + fq * 8;

    f32x4 acc[4];
#pragma unroll
    for (int n = 0; n < 4; ++n)
#pragma unroll
        for (int j = 0; j < 4; ++j) acc[n][j] = 0.f;

#pragma unroll
    for (int kt = 0; kt < 32; ++kt) {
        float4 g0 = *(const float4*)(gp + kt * 32);
        float4 g1 = *(const float4*)(gp + kt * 32 + 4);
        float4 b0 = *(const float4*)(bt + kt * 32);
        float4 b1 = *(const float4*)(bt + kt * 32 + 4);
        const float gg[8] = {g0.x, g0.y, g0.z, g0.w, g1.x, g1.y, g1.z, g1.w};
        const float bb_[8] = {b0.x, b0.y, b0.z, b0.w, b1.x, b1.y, b1.z, b1.w};
        short8 an;
#pragma unroll
        for (int j = 0; j < 8; ++j) {
            float xn = (bf2f((ushort)a[kt][j]) - mu) * rs * gg[j] + bb_[j];
            an[j] = (short)f2bf(xn);
        }
#pragma unroll
        for (int n = 0; n < 4; ++n) {
            short8 wv = *(const short8*)(Bbase + n * 16 * 1024 + kt * 32);
            acc[n] = __builtin_amdgcn_mfma_f32_16x16x32_bf16(an, wv, acc[n], 0, 0, 0);
        }
    }
#pragma unroll
    for (int n = 0; n < 4; ++n) {
        const int c = hg * 64 + n * 16 + fr;
        const float bvv = bp[c];
#pragma unroll
        for (int j = 0; j < 4; ++j)
            out[(size_t)b * 2048 * 1024 + (size_t)(m0 + fq * 4 + j) * 1024 + c] =
                acc[n][j] + bvv;
    }
}

extern "C" void kernel_launch(void* const* d_in, const int* in_sizes, int n_in,
                              void* d_out, int out_size, void* d_ws, size_t ws_size,
                              hipStream_t stream) {
    const float* v     = (const float*)d_in[0];
    const float* q     = (const float*)d_in[1];
    const float* Wa    = (const float*)d_in[2];
    const float* ba    = (const float*)d_in[3];
    const float* gamma = (const float*)d_in[4];
    const float* beta  = (const float*)d_in[5];
    const float* Wp    = (const float*)d_in[6];
    const float* bp    = (const float*)d_in[7];
    float* out = (float*)d_out;

    const size_t MB = 1ull << 20;
    char* ws = (char*)d_ws;
    ushort* qbf = (ushort*)(ws);                 //  8 MiB
    ushort* vT  = (ushort*)(ws + 8 * MB);        //  8 MiB
    ushort* WpT = (ushort*)(ws + 16 * MB);       //  2 MiB
    int NH = 1;
    {
        const int cands[5] = {16, 8, 4, 2, 1};
        for (int i = 0; i < 5; ++i) {
            if ((size_t)(18 + 28 * cands[i]) * MB <= ws_size) { NH = cands[i]; break; }
        }
    }
    ushort* WaT_c  = (ushort*)(ws + 18 * MB);
    ushort* attn_c = (ushort*)(ws + (18 + (size_t)4 * NH) * MB);
    ushort* agg_c  = (ushort*)(ws + (18 + (size_t)20 * NH) * MB);

    dim3 tb(32, 8);
    cast_bf16<<<4096, 256, 0, stream>>>(q, qbf, BATCH * LQ * DMODEL);
    transpose_cast<<<dim3(DMODEL / 32, LV / 32, BATCH), tb, 0, stream>>>(v, vT, LV, DMODEL);
    transpose_cast<<<dim3(HEAD_DIM / 32, DMODEL / 32, N_HEAD), tb, 0, stream>>>(Wp, WpT, DMODEL, HEAD_DIM);

    for (int h0 = 0; h0 < N_HEAD; h0 += NH) {
        transpose_cast<<<dim3(LV / 32, DMODEL / 32, NH), tb, 0, stream>>>(
            Wa + (size_t)h0 * DMODEL * LV, WaT_c, DMODEL, LV);

        // GEMM1: attn[z] = relu(q[b] @ WaT[h]^T + ba), M=2048 N=2048 K=1024
        // 8 bm (fastest) x 8 bn x z  -> 64 = 1<<6 blocks/z
        gemm256<true, 3, 6, true><<<64 * NH * 2, 512, 0, stream>>>(
            qbf, WaT_c, attn_c, ba + (size_t)h0 * LV, DMODEL,
            (long)LQ * DMODEL, 0L,
            0L, (long)LV * DMODEL,
            (long)LQ * LV, LV, (long)LV);

        // GEMM2: agg[z] = attn[z] @ vT[b]^T, M=2048 N=1024 K=2048
        // 4 bn (fastest) x 8 bm x z  -> 32 = 1<<5 blocks/z
        gemm256<false, 2, 5, false><<<32 * NH * 2, 512, 0, stream>>>(
            attn_c, vT, agg_c, nullptr, LV,
            (long)LQ * LV, (long)2 * LQ * LV,
            (long)DMODEL * LV, 0L,
            (long)LQ * DMODEL, DMODEL, 0L);

        // fused LayerNorm + projection + head concat -> d_out (f32)
        lnproj_kernel<<<dim3(LQ / 64, NH * 2), 256, 0, stream>>>(
            agg_c, WpT, gamma, beta, bp, out, h0);
    }
}

// Round 15
// 714.260 us; speedup vs baseline: 1.0328x; 1.0328x over previous
//
#include <hip/hip_runtime.h>
#include <hip/hip_bf16.h>

typedef __attribute__((ext_vector_type(8))) short short8;   // 8 bf16 in 4 VGPRs
typedef __attribute__((ext_vector_type(4))) float f32x4;

#define N_HEAD 16
#define DMODEL 1024
#define LV 2048
#define LQ 2048
#define BATCH 2
#define HEAD_DIM 64

template <int N> struct IC { static constexpr int v = N; };

__device__ inline ushort f2bf(float f) {
    union { float f; unsigned u; } v; v.f = f;
    unsigned r = v.u + 0x7fffu + ((v.u >> 16) & 1u);   // RNE
    return (ushort)(r >> 16);
}
__device__ inline float bf2f(ushort h) {
    union { unsigned u; float f; } v; v.u = ((unsigned)h) << 16;
    return v.f;
}

// ---------------- cast f32 -> bf16 (same layout) ----------------
__global__ __launch_bounds__(256) void cast_bf16(const float* __restrict__ src,
                                                 ushort* __restrict__ dst, int n) {
    int i = (blockIdx.x * 256 + threadIdx.x) * 4;
    if (i < n) {
        float4 v = *(const float4*)(src + i);
        ushort4 o;
        o.x = f2bf(v.x); o.y = f2bf(v.y); o.z = f2bf(v.z); o.w = f2bf(v.w);
        *(ushort4*)(dst + i) = o;
    }
}

// ---------------- transpose + cast: src[z][R][C] f32 -> dst[z][C][R] bf16 ----
__global__ __launch_bounds__(256) void transpose_cast(const float* __restrict__ src,
                                                      ushort* __restrict__ dst,
                                                      int R, int C) {
    __shared__ float t[32][33];
    size_t zoff = (size_t)blockIdx.z * R * C;
    int c0 = blockIdx.x * 32, r0 = blockIdx.y * 32;
    int tx = threadIdx.x, ty = threadIdx.y;
#pragma unroll
    for (int i = 0; i < 4; ++i)
        t[ty + i * 8][tx] = src[zoff + (size_t)(r0 + ty + i * 8) * C + c0 + tx];
    __syncthreads();
#pragma unroll
    for (int i = 0; i < 4; ++i)
        dst[zoff + (size_t)(c0 + ty + i * 8) * R + r0 + tx] = f2bf(t[tx][ty + i * 8]);
}

// -------- 256x256 batched GEMM: r7 4-phase/K64 K-loop + r10 memory fixes -----
// (round-13 verified config: 911 TF, MfmaUtil 41%, clean memory counters)
template <bool RELU, int LNA, int ZSH, bool BMFAST>
__global__ __launch_bounds__(512, 2) void gemm256(
    const ushort* __restrict__ A, const ushort* __restrict__ B,
    ushort* __restrict__ Cout, const float* __restrict__ bias,
    int K,
    long sA_b, long sA_h, long sB_b, long sB_h, long sC_z, int ldc, long sBias_h)
{
    __shared__ __align__(16) char smem[131072];

    // bijective XCD swizzle (gridDim.x % 8 == 0 always)
    const int gid = blockIdx.x;
    const int per = (int)gridDim.x >> 3;
    const int w = (gid & 7) * per + (gid >> 3);
    const int z = w >> ZSH;
    const int rem = w & ((1 << ZSH) - 1);
    int bm0, bn0;
    if (BMFAST) { bm0 = (rem & ((1 << LNA) - 1)) * 256; bn0 = (rem >> LNA) * 256; }
    else        { bn0 = (rem & ((1 << LNA) - 1)) * 256; bm0 = (rem >> LNA) * 256; }

    const int b = z & 1, h = z >> 1;
    A += (size_t)b * sA_b + (size_t)h * sA_h;
    B += (size_t)b * sB_b + (size_t)h * sB_h;
    const float* biasp = bias ? bias + (size_t)h * sBias_h : nullptr;

    const int T = threadIdx.x;
    const int lane = T & 63, wid = T >> 6;
    const int wr = wid >> 2, wc = wid & 3;          // wave -> (2 x 4) grid
    const int fr = lane & 15, fq = lane >> 4;
    const int laneoff = fr * 64 + ((fq * 16) ^ ((fr >> 3) << 5));   // swz read

    const char* pA0 = smem + 0     + wr * 8192 + laneoff;
    const char* pB0 = smem + 32768 + wc * 4096 + laneoff;
    const char* pA1 = pA0 + 65536;
    const char* pB1 = pB0 + 65536;

    const int s_row = T >> 2;                                   // 0..127
    const int s_csw = ((T & 3) * 16) ^ (((T >> 5) & 1) << 5);   // pre-swz col byte
    const ushort* gA = A + (size_t)(bm0 + s_row) * K + (s_csw >> 1);
    const ushort* gB = B + (size_t)(bn0 + s_row) * K + (s_csw >> 1);

    const int nt = K >> 6;      // K-steps of 64 (even, >= 4 here)

    auto stage = [&](int op, int kh, int db, int snext) {
        const ushort* g = op ? gB : gA;
        const size_t kbase = (size_t)snext * 64 + kh * 32;
        char* d = smem + db * 65536 + op * 32768 + kh * 16384 + (T << 4);
#pragma unroll
        for (int j = 0; j < 2; ++j) {
            __builtin_amdgcn_global_load_lds(
                (const __attribute__((address_space(1))) void*)(g + (size_t)j * 128 * K + kbase),
                (__attribute__((address_space(3))) void*)(d + j * 8192), 16, 0, 0);
        }
    };

    f32x4 acc[8][4];
#pragma unroll
    for (int m = 0; m < 8; ++m)
#pragma unroll
        for (int n = 0; n < 4; ++n)
#pragma unroll
            for (int j = 0; j < 4; ++j) acc[m][n][j] = 0.f;

    auto phase = [&](const char* pA, const char* pB, short8* bfr, int s, int db,
                     auto MH, auto KH, auto RDB, auto DOST, auto SOP, auto SKH, auto VM) {
        constexpr int mh = decltype(MH)::v, kh = decltype(KH)::v;
        short8 a[4];
#pragma unroll
        for (int i = 0; i < 4; ++i)
            a[i] = *(const short8*)(pA + kh * 16384 + (mh * 4 + i) * 1024);
        if constexpr (decltype(RDB)::v) {
#pragma unroll
            for (int n = 0; n < 4; ++n)
                bfr[n] = *(const short8*)(pB + kh * 16384 + n * 1024);
        }
        if constexpr (decltype(DOST)::v)
            stage(decltype(SOP)::v, decltype(SKH)::v, db ^ 1, s + 1);
        asm volatile("s_barrier" ::: "memory");
        asm volatile("s_waitcnt lgkmcnt(0)" ::: "memory");
        __builtin_amdgcn_sched_barrier(0);
        __builtin_amdgcn_s_setprio(1);
#pragma unroll
        for (int i = 0; i < 4; ++i)
#pragma unroll
            for (int n = 0; n < 4; ++n)
                acc[mh * 4 + i][n] = __builtin_amdgcn_mfma_f32_16x16x32_bf16(
                    a[i], bfr[n], acc[mh * 4 + i][n], 0, 0, 0);
        __builtin_amdgcn_s_setprio(0);
        __builtin_amdgcn_sched_barrier(0);
        constexpr int vm = decltype(VM)::v;
        if constexpr (vm == 4) asm volatile("s_waitcnt vmcnt(4)" ::: "memory");
        else if constexpr (vm == 0) asm volatile("s_waitcnt vmcnt(0)" ::: "memory");
        asm volatile("s_barrier" ::: "memory");
    };

    auto step_full = [&](int s, const char* pA, const char* pB, int db) {
        short8 bfr[4];
        phase(pA, pB, bfr, s, db, IC<0>{}, IC<0>{}, IC<1>{}, IC<1>{}, IC<0>{}, IC<0>{}, IC<-1>{});
        phase(pA, pB, bfr, s, db, IC<1>{}, IC<0>{}, IC<0>{}, IC<1>{}, IC<1>{}, IC<0>{}, IC<4>{});
        phase(pA, pB, bfr, s, db, IC<0>{}, IC<1>{}, IC<1>{}, IC<1>{}, IC<0>{}, IC<1>{}, IC<-1>{});
        phase(pA, pB, bfr, s, db, IC<1>{}, IC<1>{}, IC<0>{}, IC<1>{}, IC<1>{}, IC<1>{}, IC<4>{});
    };
    auto step_last = [&](int s, const char* pA, const char* pB, int db) {
        short8 bfr[4];
        phase(pA, pB, bfr, s, db, IC<0>{}, IC<0>{}, IC<1>{}, IC<0>{}, IC<0>{}, IC<0>{}, IC<-1>{});
        phase(pA, pB, bfr, s, db, IC<1>{}, IC<0>{}, IC<0>{}, IC<0>{}, IC<0>{}, IC<0>{}, IC<0>{});
        phase(pA, pB, bfr, s, db, IC<0>{}, IC<1>{}, IC<1>{}, IC<0>{}, IC<0>{}, IC<0>{}, IC<-1>{});
        phase(pA, pB, bfr, s, db, IC<1>{}, IC<1>{}, IC<0>{}, IC<0>{}, IC<0>{}, IC<0>{}, IC<-1>{});
    };

    stage(0, 0, 0, 0); stage(1, 0, 0, 0); stage(0, 1, 0, 0); stage(1, 1, 0, 0);
    asm volatile("s_waitcnt vmcnt(4)" ::: "memory");
    asm volatile("s_barrier" ::: "memory");

    for (int s = 0; s < nt - 2; s += 2) {
        step_full(s,     pA0, pB0, 0);
        step_full(s + 1, pA1, pB1, 1);
    }
    step_full(nt - 2, pA0, pB0, 0);   // stages step nt-1 into buf1
    step_last(nt - 1, pA1, pB1, 1);

    // ---- epilogue: two rounds by wr; full-line 16 B/lane stores (r10) ----
    asm volatile("s_waitcnt vmcnt(0) lgkmcnt(0)" ::: "memory");
    __builtin_amdgcn_s_barrier();
    ushort* C = Cout + (size_t)z * sC_z;
    const int col0 = bn0 + wc * 64;
    const int rl = lane >> 3, cb = lane & 7;
#pragma unroll
    for (int r = 0; r < 2; ++r) {
        if (wr == r) {
            char* eb = smem + wc * 18432;          // 128 rows x 144 B
#pragma unroll
            for (int n = 0; n < 4; ++n) {
                const float bvv = biasp ? biasp[col0 + n * 16 + fr] : 0.f;
#pragma unroll
                for (int m = 0; m < 8; ++m) {
#pragma unroll
                    for (int j = 0; j < 4; ++j) {
                        float val = acc[m][n][j] + bvv;
                        if (RELU) val = fmaxf(val, 0.f);
                        *(ushort*)(eb + (m * 16 + fq * 4 + j) * 144 + (n * 16 + fr) * 2) = f2bf(val);
                    }
                }
            }
            asm volatile("s_waitcnt lgkmcnt(0)" ::: "memory");   // per-wave region
            const int row0 = bm0 + r * 128;
#pragma unroll
            for (int i = 0; i < 16; ++i) {
                short8 vv = *(const short8*)(eb + (i * 8 + rl) * 144 + cb * 16);
                *(short8*)(C + (size_t)(row0 + i * 8 + rl) * ldc + col0 + cb * 8) = vv;
            }
        }
        __builtin_amdgcn_s_barrier();
    }
}

// -------- fused LayerNorm + projection:  out = LN(agg) @ WpT^T + bp ----------
// Two-pass version (r13-verified): pass 1 stats, pass 2 re-read (L2/L3-hot),
// normalize in-register, feed MFMA.  Single-read reg-staging variant (r14)
// REGRESSED (serializes stats->MFMA, kills occupancy) -- do not reapply.
__global__ __launch_bounds__(256) void lnproj_kernel(const ushort* __restrict__ agg,
                                                     const ushort* __restrict__ WpT,
                                                     const float* __restrict__ gamma,
                                                     const float* __restrict__ beta,
                                                     const float* __restrict__ bp,
                                                     float* __restrict__ out,
                                                     int h_base) {
    const int z = blockIdx.y, b = z & 1, hg = h_base + (z >> 1);
    const int wid = threadIdx.x >> 6, lane = threadIdx.x & 63;
    const int fr = lane & 15, fq = lane >> 4;
    const int m0 = (blockIdx.x * 4 + wid) * 16;

    const ushort* Arow = agg + ((size_t)z * 2048 + m0 + fr) * 1024 + fq * 8;

    float s = 0.f, s2 = 0.f;
    for (int kt = 0; kt < 32; ++kt) {
        short8 a = *(const short8*)(Arow + kt * 32);
#pragma unroll
        for (int j = 0; j < 8; ++j) { float x = bf2f((ushort)a[j]); s += x; s2 += x * x; }
    }
    s  += __shfl_xor(s, 16, 64);  s2 += __shfl_xor(s2, 16, 64);
    s  += __shfl_xor(s, 32, 64);  s2 += __shfl_xor(s2, 32, 64);
    const float mu  = s * (1.0f / 1024.0f);
    const float var = s2 * (1.0f / 1024.0f) - mu * mu;
    const float rs  = rsqrtf(fmaxf(var, 0.f) + 1e-5f);

    const ushort* Bbase = WpT + (size_t)hg * 64 * 1024 + (size_t)fr * 1024 + fq * 8;
    const float* gp = gamma + (size_t)hg * 1024 + fq * 8;
    const float* bt = beta  + (size_t)hg * 1024 + fq * 8;

    f32x4 acc[4];
#pragma unroll
    for (int n = 0; n < 4; ++n)
#pragma unroll
        for (int j = 0; j < 4; ++j) acc[n][j] = 0.f;

    for (int kt = 0; kt < 32; ++kt) {
        short8 a = *(const short8*)(Arow + kt * 32);
        float4 g0 = *(const float4*)(gp + kt * 32);
        float4 g1 = *(const float4*)(gp + kt * 32 + 4);
        float4 b0 = *(const float4*)(bt + kt * 32);
        float4 b1 = *(const float4*)(bt + kt * 32 + 4);
        const float gg[8] = {g0.x, g0.y, g0.z, g0.w, g1.x, g1.y, g1.z, g1.w};
        const float bb_[8] = {b0.x, b0.y, b0.z, b0.w, b1.x, b1.y, b1.z, b1.w};
        short8 an;
#pragma unroll
        for (int j = 0; j < 8; ++j) {
            float xn = (bf2f((ushort)a[j]) - mu) * rs * gg[j] + bb_[j];
            an[j] = (short)f2bf(xn);
        }
#pragma unroll
        for (int n = 0; n < 4; ++n) {
            short8 wv = *(const short8*)(Bbase + n * 16 * 1024 + kt * 32);
            acc[n] = __builtin_amdgcn_mfma_f32_16x16x32_bf16(an, wv, acc[n], 0, 0, 0);
        }
    }
#pragma unroll
    for (int n = 0; n < 4; ++n) {
        const int c = hg * 64 + n * 16 + fr;
        const float bvv = bp[c];
#pragma unroll
        for (int j = 0; j < 4; ++j)
            out[(size_t)b * 2048 * 1024 + (size_t)(m0 + fq * 4 + j) * 1024 + c] =
                acc[n][j] + bvv;
    }
}

extern "C" void kernel_launch(void* const* d_in, const int* in_sizes, int n_in,
                              void* d_out, int out_size, void* d_ws, size_t ws_size,
                              hipStream_t stream) {
    const float* v     = (const float*)d_in[0];
    const float* q     = (const float*)d_in[1];
    const float* Wa    = (const float*)d_in[2];
    const float* ba    = (const float*)d_in[3];
    const float* gamma = (const float*)d_in[4];
    const float* beta  = (const float*)d_in[5];
    const float* Wp    = (const float*)d_in[6];
    const float* bp    = (const float*)d_in[7];
    float* out = (float*)d_out;

    const size_t MB = 1ull << 20;
    char* ws = (char*)d_ws;
    ushort* qbf = (ushort*)(ws);                 //  8 MiB
    ushort* vT  = (ushort*)(ws + 8 * MB);        //  8 MiB
    ushort* WpT = (ushort*)(ws + 16 * MB);       //  2 MiB
    int NH = 1;
    {
        const int cands[5] = {16, 8, 4, 2, 1};
        for (int i = 0; i < 5; ++i) {
            if ((size_t)(18 + 28 * cands[i]) * MB <= ws_size) { NH = cands[i]; break; }
        }
    }
    ushort* WaT_c  = (ushort*)(ws + 18 * MB);
    ushort* attn_c = (ushort*)(ws + (18 + (size_t)4 * NH) * MB);
    ushort* agg_c  = (ushort*)(ws + (18 + (size_t)20 * NH) * MB);

    dim3 tb(32, 8);
    cast_bf16<<<4096, 256, 0, stream>>>(q, qbf, BATCH * LQ * DMODEL);
    transpose_cast<<<dim3(DMODEL / 32, LV / 32, BATCH), tb, 0, stream>>>(v, vT, LV, DMODEL);
    transpose_cast<<<dim3(HEAD_DIM / 32, DMODEL / 32, N_HEAD), tb, 0, stream>>>(Wp, WpT, DMODEL, HEAD_DIM);

    for (int h0 = 0; h0 < N_HEAD; h0 += NH) {
        transpose_cast<<<dim3(LV / 32, DMODEL / 32, NH), tb, 0, stream>>>(
            Wa + (size_t)h0 * DMODEL * LV, WaT_c, DMODEL, LV);

        // GEMM1: attn[z] = relu(q[b] @ WaT[h]^T + ba), M=2048 N=2048 K=1024
        // 8 bm (fastest) x 8 bn x z  -> 64 = 1<<6 blocks/z
        gemm256<true, 3, 6, true><<<64 * NH * 2, 512, 0, stream>>>(
            qbf, WaT_c, attn_c, ba + (size_t)h0 * LV, DMODEL,
            (long)LQ * DMODEL, 0L,
            0L, (long)LV * DMODEL,
            (long)LQ * LV, LV, (long)LV);

        // GEMM2: agg[z] = attn[z] @ vT[b]^T, M=2048 N=1024 K=2048
        // 4 bn (fastest) x 8 bm x z  -> 32 = 1<<5 blocks/z
        gemm256<false, 2, 5, false><<<32 * NH * 2, 512, 0, stream>>>(
            attn_c, vT, agg_c, nullptr, LV,
            (long)LQ * LV, (long)2 * LQ * LV,
            (long)DMODEL * LV, 0L,
            (long)LQ * DMODEL, DMODEL, 0L);

        // fused LayerNorm + projection + head concat -> d_out (f32)
        lnproj_kernel<<<dim3(LQ / 64, NH * 2), 256, 0, stream>>>(
            agg_c, WpT, gamma, beta, bp, out, h0);
    }
}